// Round 1
// baseline (1735.207 us; speedup 1.0000x reference)
//
#include <hip/hip_runtime.h>
#include <math.h>

#define NB 8
#define NH 8
#define NT 1024
#define DMODEL 512

// ---------------- mask weights ----------------
__global__ __launch_bounds__(256) void k_maskw(
    const float* __restrict__ Wq, const float* __restrict__ Wk,
    const float* __restrict__ Wv, const float* __restrict__ WO,
    const int* __restrict__ g, float* __restrict__ Wqkv_m, float* __restrict__ WO_m)
{
  int stride = gridDim.x * 256;
  int tid0 = blockIdx.x * 256 + threadIdx.x;
  for (int i = tid0; i < 1536 * 512; i += stride) {
    int m = i & 511;
    int j = i >> 9;            // row: qkv*512 + h*64 + k
    int k = j & 63;
    int hh = (j >> 6) & 7;
    int qkv = j >> 9;
    const float* W = (qkv == 0) ? Wq : (qkv == 1 ? Wk : Wv);
    Wqkv_m[i] = W[(hh * 64 + k) * 512 + m] * (float)g[k * 64 + (m & 63)];
  }
  for (int i = tid0; i < 512 * 512; i += stride) {
    int d = i & 511, e = i >> 9;
    WO_m[i] = WO[i] * (float)g[(e & 63) * 64 + (d & 63)];
  }
}

// ---------------- generic fp32 GEMM: C[M,N] = A[M,K] * Bm[N,K]^T ----------------
template<bool EPI>
__global__ __launch_bounds__(256) void k_gemm(
    const float* __restrict__ A, const float* __restrict__ Bm, float* __restrict__ C,
    int M, int N, int K, int ldc,
    const float* __restrict__ X, const float* __restrict__ bias)
{
  __shared__ float At[16][132];
  __shared__ float Bt[16][132];
  const int bm = blockIdx.y * 128;
  const int bn = blockIdx.x * 128;
  const int tid = threadIdx.x;
  const int tx = tid & 15, ty = tid >> 4;
  float acc[8][8] = {};
  for (int k0 = 0; k0 < K; k0 += 16) {
#pragma unroll
    for (int l = 0; l < 2; ++l) {
      int li = tid + l * 256;
      int r = li >> 2, c4 = (li & 3) << 2;
      float4 av = *(const float4*)(A + (size_t)(bm + r) * K + k0 + c4);
      At[c4 + 0][r] = av.x; At[c4 + 1][r] = av.y; At[c4 + 2][r] = av.z; At[c4 + 3][r] = av.w;
      float4 bv = *(const float4*)(Bm + (size_t)(bn + r) * K + k0 + c4);
      Bt[c4 + 0][r] = bv.x; Bt[c4 + 1][r] = bv.y; Bt[c4 + 2][r] = bv.z; Bt[c4 + 3][r] = bv.w;
    }
    __syncthreads();
#pragma unroll
    for (int kk = 0; kk < 16; ++kk) {
      float a[8], b[8];
      *(float4*)&a[0] = *(const float4*)&At[kk][ty * 4];
      *(float4*)&a[4] = *(const float4*)&At[kk][ty * 4 + 64];
      *(float4*)&b[0] = *(const float4*)&Bt[kk][tx * 4];
      *(float4*)&b[4] = *(const float4*)&Bt[kk][tx * 4 + 64];
#pragma unroll
      for (int i = 0; i < 8; ++i)
#pragma unroll
        for (int j = 0; j < 8; ++j)
          acc[i][j] = fmaf(a[i], b[j], acc[i][j]);
    }
    __syncthreads();
  }
#pragma unroll
  for (int ib = 0; ib < 2; ++ib)
#pragma unroll
    for (int i = 0; i < 4; ++i) {
      int r = bm + ib * 64 + ty * 4 + i;
#pragma unroll
      for (int jb = 0; jb < 2; ++jb) {
        int c = bn + jb * 64 + tx * 4;
        float4 v;
        v.x = acc[ib * 4 + i][jb * 4 + 0];
        v.y = acc[ib * 4 + i][jb * 4 + 1];
        v.z = acc[ib * 4 + i][jb * 4 + 2];
        v.w = acc[ib * 4 + i][jb * 4 + 3];
        if (EPI) {
          float4 xv = *(const float4*)(X + (size_t)r * ldc + c);
          float4 bb = *(const float4*)(bias + c);
          v.x += xv.x + bb.x; v.y += xv.y + bb.y; v.z += xv.z + bb.z; v.w += xv.w + bb.w;
        }
        *(float4*)(C + (size_t)r * ldc + c) = v;
      }
    }
}

// ---------------- combine QKV: bias + l2norm(Q,K), reshape to [bh][t][64] ----------------
__global__ __launch_bounds__(256) void k_combine_qkv(
    const float* __restrict__ raw, const float* __restrict__ bq,
    const float* __restrict__ bk, const float* __restrict__ bv,
    float* __restrict__ Qf, float* __restrict__ Kf, float* __restrict__ Vf)
{
  int wid = (blockIdx.x * 256 + threadIdx.x) >> 6;
  int lane = threadIdx.x & 63;
  int nw = (gridDim.x * 256) >> 6;
  const int total = NB * NT * 24;
  for (int v = wid; v < total; v += nw) {
    int bt = v / 24;
    int rem = v % 24;
    int qkv = rem >> 3, hh = rem & 7;
    float val = raw[(size_t)bt * 1536 + qkv * 512 + hh * 64 + lane];
    const float* bias = (qkv == 0) ? bq : (qkv == 1 ? bk : bv);
    val += bias[hh * 64 + lane];
    if (qkv < 2) {
      float ss = val * val;
#pragma unroll
      for (int off = 32; off; off >>= 1) ss += __shfl_xor(ss, off);
      val /= fmaxf(sqrtf(ss), 1e-12f);
    }
    float* dst = (qkv == 0) ? Qf : (qkv == 1 ? Kf : Vf);
    int b = bt >> 10, t = bt & 1023;
    dst[(((size_t)(b * 8 + hh) * NT) + t) * 64 + lane] = val;
  }
}

// ---------------- combine aux/pos: bias + l2norm + fold wa/wp, to [bh][t][48] ----------------
__global__ __launch_bounds__(256) void k_combine_ap(
    const float* __restrict__ rawA, const float* __restrict__ rawP,
    const float* __restrict__ bqa, const float* __restrict__ bka,
    const float* __restrict__ bqp, const float* __restrict__ bkp,
    const float* __restrict__ wa, const float* __restrict__ wp,
    float* __restrict__ qcf, float* __restrict__ kcf)
{
  const float wa0 = wa[0], wp0 = wp[0];
  int wid = (blockIdx.x * 256 + threadIdx.x) >> 6;
  int lane = threadIdx.x & 63;
  int nw = (gridDim.x * 256) >> 6;
  const int total = NB * NT * NH;
  for (int v = wid; v < total; v += nw) {
    int bt = v >> 3, hh = v & 7;
    int b = bt >> 10, t = bt & 1023;
    size_t obase = (((size_t)(b * 8 + hh) * NT) + t) * 48;
    {
      int c = lane & 31;
      bool isK = lane >= 32;
      float val = rawA[(size_t)bt * 512 + (isK ? 256 : 0) + hh * 32 + c];
      val += (isK ? bka : bqa)[hh * 32 + c];
      float ss = val * val;
#pragma unroll
      for (int off = 16; off; off >>= 1) ss += __shfl_xor(ss, off, 32);
      val /= fmaxf(sqrtf(ss), 1e-12f);
      if (isK) kcf[obase + c] = val; else qcf[obase + c] = wa0 * val;
    }
    {
      int c = lane & 15;
      int grp = lane >> 4;
      if (grp < 2) {
        float val = rawP[(size_t)bt * 256 + (grp ? 128 : 0) + hh * 16 + c];
        val += (grp ? bkp : bqp)[hh * 16 + c];
        float ss = val * val;
#pragma unroll
        for (int off = 8; off; off >>= 1) ss += __shfl_xor(ss, off, 16);
        val /= fmaxf(sqrtf(ss), 1e-12f);
        if (grp) kcf[obase + 32 + c] = val; else qcf[obase + 32 + c] = wp0 * val;
      }
    }
  }
}

// ---------------- sim kernel: S (haloed) + tn + qc.kc + online row stats ----------------
__global__ __launch_bounds__(256) void k_sim(
    const float* __restrict__ Qf, const float* __restrict__ Kf,
    const float* __restrict__ qcf, const float* __restrict__ kcf,
    const float* __restrict__ w, float* __restrict__ ml, float* __restrict__ attn)
{
  __shared__ float Qe[64][80];   // [k][ext_row]
  __shared__ float Ke[64][80];
  __shared__ float Se[80][81];
  __shared__ float qc_t[48][64];
  __shared__ float kc_t[48][64];
  __shared__ float Pd[64][65];
  __shared__ float mrow[64], lrow[64];
  const int at = blockIdx.x, bh = blockIdx.y;
  const int a0 = at * 64;
  const int b = bh >> 3, hh = bh & 7;
  const int tid = threadIdx.x;
  const float w0 = w[0];
  if (tid < 64) { mrow[tid] = -INFINITY; lrow[tid] = 0.0f; }
  // load Qe (transposed, zero-padded halo rows)
  for (int idx = tid; idx < 80 * 16; idx += 256) {
    int r = idx >> 4, c4 = (idx & 15) << 2;
    int ga = a0 - 8 + r;
    float4 v = make_float4(0.f, 0.f, 0.f, 0.f);
    if ((unsigned)ga < (unsigned)NT) v = *(const float4*)(Qf + ((size_t)bh * NT + ga) * 64 + c4);
    Qe[c4 + 0][r] = v.x; Qe[c4 + 1][r] = v.y; Qe[c4 + 2][r] = v.z; Qe[c4 + 3][r] = v.w;
  }
  for (int idx = tid; idx < 64 * 12; idx += 256) {
    int r = idx / 12, c4 = (idx % 12) << 2;
    float4 v = *(const float4*)(qcf + ((size_t)bh * NT + a0 + r) * 48 + c4);
    qc_t[c4 + 0][r] = v.x; qc_t[c4 + 1][r] = v.y; qc_t[c4 + 2][r] = v.z; qc_t[c4 + 3][r] = v.w;
  }
  const int u = tid >> 4, vv = tid & 15;
  const int g = tid & 63, wv = tid >> 6;
  for (int ct = 0; ct < 16; ++ct) {
    const int c0 = ct * 64;
    for (int idx = tid; idx < 80 * 16; idx += 256) {
      int r = idx >> 4, c4 = (idx & 15) << 2;
      int gc = c0 - 8 + r;
      float4 v = make_float4(0.f, 0.f, 0.f, 0.f);
      if ((unsigned)gc < (unsigned)NT) v = *(const float4*)(Kf + ((size_t)bh * NT + gc) * 64 + c4);
      Ke[c4 + 0][r] = v.x; Ke[c4 + 1][r] = v.y; Ke[c4 + 2][r] = v.z; Ke[c4 + 3][r] = v.w;
    }
    for (int idx = tid; idx < 64 * 12; idx += 256) {
      int r = idx / 12, c4 = (idx % 12) << 2;
      float4 v = *(const float4*)(kcf + ((size_t)bh * NT + c0 + r) * 48 + c4);
      kc_t[c4 + 0][r] = v.x; kc_t[c4 + 1][r] = v.y; kc_t[c4 + 2][r] = v.z; kc_t[c4 + 3][r] = v.w;
    }
    __syncthreads();
    // S: 80x80 ext tile, 5x5 per thread
    {
      float acc[5][5] = {};
      for (int kk = 0; kk < 64; ++kk) {
        float qa[5], kb[5];
#pragma unroll
        for (int i = 0; i < 5; ++i) qa[i] = Qe[kk][u * 5 + i];
#pragma unroll
        for (int j = 0; j < 5; ++j) kb[j] = Ke[kk][vv * 5 + j];
#pragma unroll
        for (int i = 0; i < 5; ++i)
#pragma unroll
          for (int j = 0; j < 5; ++j)
            acc[i][j] = fmaf(qa[i], kb[j], acc[i][j]);
      }
#pragma unroll
      for (int i = 0; i < 5; ++i)
#pragma unroll
        for (int j = 0; j < 5; ++j)
          Se[u * 5 + i][vv * 5 + j] = acc[i][j];
    }
    // Pd = qc.kc (64x64, 4x4 per thread)
    {
      float pacc[4][4] = {};
      for (int kk = 0; kk < 48; ++kk) {
        float pa[4], pb[4];
#pragma unroll
        for (int i = 0; i < 4; ++i) pa[i] = qc_t[kk][u * 4 + i];
#pragma unroll
        for (int j = 0; j < 4; ++j) pb[j] = kc_t[kk][vv * 4 + j];
#pragma unroll
        for (int i = 0; i < 4; ++i)
#pragma unroll
          for (int j = 0; j < 4; ++j)
            pacc[i][j] = fmaf(pa[i], pb[j], pacc[i][j]);
      }
#pragma unroll
      for (int i = 0; i < 4; ++i)
#pragma unroll
        for (int j = 0; j < 4; ++j)
          Pd[u * 4 + i][vv * 4 + j] = pacc[i][j];
    }
    __syncthreads();
    // tn (diagonal sliding window) + sim + online stats + store
    {
      float num = 0.f;
      for (int s = 0; s < 16; ++s) {
        int a_l = wv * 16 + s;
        int c_l = (a_l + g) & 63;
        if (s == 0 || c_l == 0) {
          num = 0.f;
#pragma unroll
          for (int t = 0; t <= 16; ++t) num += Se[a_l + t][c_l + t];
        } else {
          num += Se[a_l + 16][c_l + 16] - Se[a_l - 1][c_l - 1];
        }
        int a = a0 + a_l, c = c0 + c_l;
        int mn = min(a, c), mx = max(a, c);
        float cnt = (float)(min(8, mn) + min(8, 1023 - mx) + 1);
        float sim = w0 * num / cnt + Pd[a_l][c_l];
        float tmax = sim;
#pragma unroll
        for (int off = 32; off; off >>= 1) tmax = fmaxf(tmax, __shfl_xor(tmax, off));
        float m_old = mrow[a_l];
        float m_new = fmaxf(m_old, tmax);
        float pe = __expf(sim - m_new);
        float ps = pe;
#pragma unroll
        for (int off = 32; off; off >>= 1) ps += __shfl_xor(ps, off);
        if (g == 0) {
          lrow[a_l] = lrow[a_l] * __expf(m_old - m_new) + ps;
          mrow[a_l] = m_new;
        }
        attn[(((size_t)(b * NT + a)) * NH + hh) * NT + c] = sim;
      }
    }
    __syncthreads();
  }
  if (tid < 64) {
    ml[((size_t)bh * NT + a0 + tid) * 2] = mrow[tid];
    ml[((size_t)bh * NT + a0 + tid) * 2 + 1] = lrow[tid];
  }
}

// ---------------- softmax finalize + PV ----------------
__global__ __launch_bounds__(256) void k_pv(
    const float* __restrict__ Vf, const float* __restrict__ ml,
    float* __restrict__ attn, float* __restrict__ deta)
{
  __shared__ float Pt[64][65];   // [c][a] transposed p
  __shared__ float Vt[64][68];   // [c][k]
  __shared__ float msh[64], lsh[64];
  const int at = blockIdx.x, bh = blockIdx.y;
  const int a0 = at * 64;
  const int b = bh >> 3, hh = bh & 7;
  const int tid = threadIdx.x;
  if (tid < 64) {
    msh[tid] = ml[((size_t)bh * NT + a0 + tid) * 2];
    lsh[tid] = 1.0f / ml[((size_t)bh * NT + a0 + tid) * 2 + 1];
  }
  float acc[4][4] = {};
  const int u = tid >> 4, v = tid & 15;
  for (int ct = 0; ct < 16; ++ct) {
    const int c0 = ct * 64;
    __syncthreads();
#pragma unroll
    for (int l4 = 0; l4 < 4; ++l4) {
      int idx = tid + l4 * 256;
      int r = idx >> 4, c4 = (idx & 15) << 2;
      size_t gaddr = (((size_t)(b * NT + a0 + r)) * NH + hh) * NT + c0 + c4;
      float4 sv = *(const float4*)(attn + gaddr);
      float m = msh[r], rl = lsh[r];
      float4 pv;
      pv.x = __expf(sv.x - m) * rl;
      pv.y = __expf(sv.y - m) * rl;
      pv.z = __expf(sv.z - m) * rl;
      pv.w = __expf(sv.w - m) * rl;
      *(float4*)(attn + gaddr) = pv;
      Pt[c4 + 0][r] = pv.x; Pt[c4 + 1][r] = pv.y; Pt[c4 + 2][r] = pv.z; Pt[c4 + 3][r] = pv.w;
      float4 vvv = *(const float4*)(Vf + ((size_t)bh * NT + c0 + r) * 64 + c4);
      *(float4*)&Vt[r][c4] = vvv;
    }
    __syncthreads();
    for (int cc = 0; cc < 64; ++cc) {
      float pa[4], vb[4];
#pragma unroll
      for (int i = 0; i < 4; ++i) pa[i] = Pt[cc][u * 4 + i];
      *(float4*)&vb[0] = *(const float4*)&Vt[cc][v * 4];
#pragma unroll
      for (int i = 0; i < 4; ++i)
#pragma unroll
        for (int j = 0; j < 4; ++j)
          acc[i][j] = fmaf(pa[i], vb[j], acc[i][j]);
    }
  }
#pragma unroll
  for (int i = 0; i < 4; ++i) {
    int a = a0 + u * 4 + i;
    float4 o;
    o.x = acc[i][0]; o.y = acc[i][1]; o.z = acc[i][2]; o.w = acc[i][3];
    *(float4*)(deta + ((size_t)(b * NT + a)) * DMODEL + hh * 64 + v * 4) = o;
  }
}

extern "C" void kernel_launch(void* const* d_in, const int* in_sizes, int n_in,
                              void* d_out, int out_size, void* d_ws, size_t ws_size,
                              hipStream_t stream) {
  const float* x   = (const float*)d_in[0];
  const float* aux = (const float*)d_in[1];
  const float* pos = (const float*)d_in[2];
  const float* Wq  = (const float*)d_in[3];
  const float* bq  = (const float*)d_in[4];
  const float* Wk  = (const float*)d_in[5];
  const float* bk  = (const float*)d_in[6];
  const float* Wv  = (const float*)d_in[7];
  const float* bv  = (const float*)d_in[8];
  const float* Wqa = (const float*)d_in[9];
  const float* bqa = (const float*)d_in[10];
  const float* Wka = (const float*)d_in[11];
  const float* bka = (const float*)d_in[12];
  const float* Wqp = (const float*)d_in[13];
  const float* bqp = (const float*)d_in[14];
  const float* Wkp = (const float*)d_in[15];
  const float* bkp = (const float*)d_in[16];
  const float* WO  = (const float*)d_in[17];
  const float* bO  = (const float*)d_in[18];
  const float* w   = (const float*)d_in[19];
  const float* wa  = (const float*)d_in[20];
  const float* wp  = (const float*)d_in[21];
  const int*   gdep = (const int*)d_in[22];

  float* out  = (float*)d_out;                        // [8,1024,512]
  float* attn = out + (size_t)4194304;                // [8,1024,8,1024]
  float* deta = out + (size_t)71303168;               // [8,1024,512]

  // temp raw GEMM outputs live in the (not yet written) attn region
  float* QKVraw = attn;                               // [8192,1536]
  float* APraw  = attn + (size_t)12582912;            // [8192,512]
  float* PPraw  = APraw + (size_t)4194304;            // [8192,256]

  // aliases: Qf -> out slot, Kf -> deta slot (both dead before overwrite)
  float* Qf = out;
  float* Kf = deta;

  float* ws = (float*)d_ws;
  float* Wqkv_m = ws;                                 // 786432
  float* WO_m   = Wqkv_m + 786432;                    // 262144
  float* Vf     = WO_m + 262144;                      // 4194304
  float* qcf    = Vf + 4194304;                       // 3145728
  float* kcf    = qcf + 3145728;                      // 3145728
  float* ml     = kcf + 3145728;                      // 131072

  k_maskw<<<512, 256, 0, stream>>>(Wq, Wk, Wv, WO, gdep, Wqkv_m, WO_m);
  k_gemm<false><<<dim3(12, 64), 256, 0, stream>>>(x, Wqkv_m, QKVraw, 8192, 1536, 512, 1536, nullptr, nullptr);
  k_gemm<false><<<dim3(2, 64), 256, 0, stream>>>(aux, Wqa, APraw, 8192, 256, 256, 512, nullptr, nullptr);
  k_gemm<false><<<dim3(2, 64), 256, 0, stream>>>(aux, Wka, APraw + 256, 8192, 256, 256, 512, nullptr, nullptr);
  k_gemm<false><<<dim3(1, 64), 256, 0, stream>>>(pos, Wqp, PPraw, 8192, 128, 128, 256, nullptr, nullptr);
  k_gemm<false><<<dim3(1, 64), 256, 0, stream>>>(pos, Wkp, PPraw + 128, 8192, 128, 128, 256, nullptr, nullptr);
  k_combine_qkv<<<1024, 256, 0, stream>>>(QKVraw, bq, bk, bv, Qf, Kf, Vf);
  k_combine_ap<<<1024, 256, 0, stream>>>(APraw, PPraw, bqa, bka, bqp, bkp, wa, wp, qcf, kcf);
  k_sim<<<dim3(16, 64), 256, 0, stream>>>(Qf, Kf, qcf, kcf, w, ml, attn);
  k_pv<<<dim3(16, 64), 256, 0, stream>>>(Vf, ml, attn, deta);
  k_gemm<true><<<dim3(4, 64), 256, 0, stream>>>(deta, WO_m, out, 8192, 512, 512, 512, x, bO);
}

// Round 2
// 927.695 us; speedup vs baseline: 1.8704x; 1.8704x over previous
//
#include <hip/hip_runtime.h>
#include <math.h>

#define NB 8
#define NH 8
#define NT 1024
#define DMODEL 512

typedef short bh8 __attribute__((ext_vector_type(8)));   // 8 bf16 in shorts (4 VGPRs)
typedef float fx4 __attribute__((ext_vector_type(4)));   // MFMA accumulator

__device__ __forceinline__ unsigned short f2bf(float f) {
  union { float f; unsigned int u; } v; v.f = f;
  unsigned int u = v.u + 0x7FFFu + ((v.u >> 16) & 1u);
  return (unsigned short)(u >> 16);
}
__device__ __forceinline__ float bf2f(unsigned short h) {
  union { unsigned int u; float f; } v; v.u = ((unsigned int)h) << 16;
  return v.f;
}

// ---------------- mask weights ----------------
__global__ __launch_bounds__(256) void k_maskw(
    const float* __restrict__ Wq, const float* __restrict__ Wk,
    const float* __restrict__ Wv, const float* __restrict__ WO,
    const int* __restrict__ g, float* __restrict__ Wqkv_m, float* __restrict__ WO_m)
{
  int stride = gridDim.x * 256;
  int tid0 = blockIdx.x * 256 + threadIdx.x;
  for (int i = tid0; i < 1536 * 512; i += stride) {
    int m = i & 511;
    int j = i >> 9;            // row: qkv*512 + h*64 + k
    int k = j & 63;
    int hh = (j >> 6) & 7;
    int qkv = j >> 9;
    const float* W = (qkv == 0) ? Wq : (qkv == 1 ? Wk : Wv);
    Wqkv_m[i] = W[(hh * 64 + k) * 512 + m] * (float)g[k * 64 + (m & 63)];
  }
  for (int i = tid0; i < 512 * 512; i += stride) {
    int d = i & 511, e = i >> 9;
    WO_m[i] = WO[i] * (float)g[(e & 63) * 64 + (d & 63)];
  }
}

// ---------------- generic fp32 GEMM: C[M,N] = A[M,K] * Bm[N,K]^T ----------------
template<bool EPI>
__global__ __launch_bounds__(256) void k_gemm(
    const float* __restrict__ A, const float* __restrict__ Bm, float* __restrict__ C,
    int M, int N, int K, int ldc,
    const float* __restrict__ X, const float* __restrict__ bias)
{
  __shared__ float At[16][132];
  __shared__ float Bt[16][132];
  const int bm = blockIdx.y * 128;
  const int bn = blockIdx.x * 128;
  const int tid = threadIdx.x;
  const int tx = tid & 15, ty = tid >> 4;
  float acc[8][8] = {};
  for (int k0 = 0; k0 < K; k0 += 16) {
#pragma unroll
    for (int l = 0; l < 2; ++l) {
      int li = tid + l * 256;
      int r = li >> 2, c4 = (li & 3) << 2;
      float4 av = *(const float4*)(A + (size_t)(bm + r) * K + k0 + c4);
      At[c4 + 0][r] = av.x; At[c4 + 1][r] = av.y; At[c4 + 2][r] = av.z; At[c4 + 3][r] = av.w;
      float4 bv = *(const float4*)(Bm + (size_t)(bn + r) * K + k0 + c4);
      Bt[c4 + 0][r] = bv.x; Bt[c4 + 1][r] = bv.y; Bt[c4 + 2][r] = bv.z; Bt[c4 + 3][r] = bv.w;
    }
    __syncthreads();
#pragma unroll
    for (int kk = 0; kk < 16; ++kk) {
      float a[8], b[8];
      *(float4*)&a[0] = *(const float4*)&At[kk][ty * 4];
      *(float4*)&a[4] = *(const float4*)&At[kk][ty * 4 + 64];
      *(float4*)&b[0] = *(const float4*)&Bt[kk][tx * 4];
      *(float4*)&b[4] = *(const float4*)&Bt[kk][tx * 4 + 64];
#pragma unroll
      for (int i = 0; i < 8; ++i)
#pragma unroll
        for (int j = 0; j < 8; ++j)
          acc[i][j] = fmaf(a[i], b[j], acc[i][j]);
    }
    __syncthreads();
  }
#pragma unroll
  for (int ib = 0; ib < 2; ++ib)
#pragma unroll
    for (int i = 0; i < 4; ++i) {
      int r = bm + ib * 64 + ty * 4 + i;
#pragma unroll
      for (int jb = 0; jb < 2; ++jb) {
        int c = bn + jb * 64 + tx * 4;
        float4 v;
        v.x = acc[ib * 4 + i][jb * 4 + 0];
        v.y = acc[ib * 4 + i][jb * 4 + 1];
        v.z = acc[ib * 4 + i][jb * 4 + 2];
        v.w = acc[ib * 4 + i][jb * 4 + 3];
        if (EPI) {
          float4 xv = *(const float4*)(X + (size_t)r * ldc + c);
          float4 bb = *(const float4*)(bias + c);
          v.x += xv.x + bb.x; v.y += xv.y + bb.y; v.z += xv.z + bb.z; v.w += xv.w + bb.w;
        }
        *(float4*)(C + (size_t)r * ldc + c) = v;
      }
    }
}

// ---------------- combine QKV: bias + l2norm(Q,K) -> bf16, V fp32, [bh][t][64] ----------------
__global__ __launch_bounds__(256) void k_combine_qkv(
    const float* __restrict__ raw, const float* __restrict__ bq,
    const float* __restrict__ bk, const float* __restrict__ bv,
    unsigned short* __restrict__ Qf, unsigned short* __restrict__ Kf,
    float* __restrict__ Vf)
{
  int wid = (blockIdx.x * 256 + threadIdx.x) >> 6;
  int lane = threadIdx.x & 63;
  int nw = (gridDim.x * 256) >> 6;
  const int total = NB * NT * 24;
  for (int v = wid; v < total; v += nw) {
    int bt = v / 24;
    int rem = v % 24;
    int qkv = rem >> 3, hh = rem & 7;
    float val = raw[(size_t)bt * 1536 + qkv * 512 + hh * 64 + lane];
    const float* bias = (qkv == 0) ? bq : (qkv == 1 ? bk : bv);
    val += bias[hh * 64 + lane];
    int b = bt >> 10, t = bt & 1023;
    size_t o = (((size_t)(b * 8 + hh) * NT) + t) * 64 + lane;
    if (qkv < 2) {
      float ss = val * val;
#pragma unroll
      for (int off = 32; off; off >>= 1) ss += __shfl_xor(ss, off);
      val /= fmaxf(sqrtf(ss), 1e-12f);
      if (qkv == 0) Qf[o] = f2bf(val); else Kf[o] = f2bf(val);
    } else {
      Vf[o] = val;
    }
  }
}

// ---------------- combine aux/pos: bias + l2norm + fold wa/wp -> bf16 [bh][t][64] (48..63 = 0) ----------------
__global__ __launch_bounds__(256) void k_combine_ap(
    const float* __restrict__ rawA, const float* __restrict__ rawP,
    const float* __restrict__ bqa, const float* __restrict__ bka,
    const float* __restrict__ bqp, const float* __restrict__ bkp,
    const float* __restrict__ wa, const float* __restrict__ wp,
    unsigned short* __restrict__ qcf, unsigned short* __restrict__ kcf)
{
  const float wa0 = wa[0], wp0 = wp[0];
  int wid = (blockIdx.x * 256 + threadIdx.x) >> 6;
  int lane = threadIdx.x & 63;
  int nw = (gridDim.x * 256) >> 6;
  const int total = NB * NT * NH;
  for (int v = wid; v < total; v += nw) {
    int bt = v >> 3, hh = v & 7;
    int b = bt >> 10, t = bt & 1023;
    size_t obase = (((size_t)(b * 8 + hh) * NT) + t) * 64;
    {
      int c = lane & 31;
      bool isK = lane >= 32;
      float val = rawA[(size_t)bt * 512 + (isK ? 256 : 0) + hh * 32 + c];
      val += (isK ? bka : bqa)[hh * 32 + c];
      float ss = val * val;
#pragma unroll
      for (int off = 16; off; off >>= 1) ss += __shfl_xor(ss, off, 32);
      val /= fmaxf(sqrtf(ss), 1e-12f);
      if (isK) kcf[obase + c] = f2bf(val); else qcf[obase + c] = f2bf(wa0 * val);
    }
    {
      int c = lane & 15;
      int grp = lane >> 4;
      if (grp < 2) {
        float val = rawP[(size_t)bt * 256 + (grp ? 128 : 0) + hh * 16 + c];
        val += (grp ? bkp : bqp)[hh * 16 + c];
        float ss = val * val;
#pragma unroll
        for (int off = 8; off; off >>= 1) ss += __shfl_xor(ss, off, 16);
        val /= fmaxf(sqrtf(ss), 1e-12f);
        if (grp) kcf[obase + 32 + c] = f2bf(val); else qcf[obase + 32 + c] = f2bf(wp0 * val);
      } else if (grp == 2) {
        qcf[obase + 48 + c] = 0;
      } else {
        kcf[obase + 48 + c] = 0;
      }
    }
  }
}

// ---------------- sim kernel: MFMA S-ext + MFMA Pd + diagonal slide + online stats ----------------
__global__ __launch_bounds__(256) void k_sim(
    const unsigned short* __restrict__ Qf, const unsigned short* __restrict__ Kf,
    const unsigned short* __restrict__ qcf, const unsigned short* __restrict__ kcf,
    const float* __restrict__ w, float* __restrict__ ml, float* __restrict__ attn)
{
  __shared__ float Se[80][81];              // S ext tile (rows a0-8.., cols c0-8..)
  __shared__ unsigned short Pd[64][66];     // aux+pos dot, bf16
  __shared__ float mrow[64], lrow[64];
  const int at = blockIdx.x, bh = blockIdx.y;
  const int a0 = at * 64;
  const int b = bh >> 3, hh = bh & 7;
  const int tid = threadIdx.x;
  const int lane = tid & 63, wv = tid >> 6;
  const int lrow16 = lane & 15, lgrp = lane >> 4;
  const float w0 = w[0];
  if (tid < 64) { mrow[tid] = -INFINITY; lrow[tid] = 0.0f; }

  const bh8 zfrag = {0, 0, 0, 0, 0, 0, 0, 0};

  // hoisted qc A-frags for Pd (constant across c-tiles): rows wv*16..+16
  bh8 qa0, qa1;
  {
    const unsigned short* qb =
        qcf + ((size_t)bh * NT + a0 + wv * 16 + lrow16) * 64 + lgrp * 8;
    qa0 = *(const bh8*)(qb);
    qa1 = *(const bh8*)(qb + 32);
  }

  for (int ct = 0; ct < 16; ++ct) {
    const int c0 = ct * 64;
    __syncthreads();   // previous slide phase done reading Se/Pd

    // ---- Se: 25 ext tiles (16x16), round-robin over 4 waves ----
#pragma unroll
    for (int i = 0; i < 7; ++i) {
      int tt = wv + 4 * i;
      if (tt < 25) {
        int tr = tt / 5, tc = tt % 5;
        int ar = a0 - 8 + tr * 16 + lrow16;
        int kr = c0 - 8 + tc * 16 + lrow16;
        bool av = (unsigned)ar < (unsigned)NT;
        bool bv = (unsigned)kr < (unsigned)NT;
        const unsigned short* ap = Qf + ((size_t)bh * NT + (av ? ar : 0)) * 64 + lgrp * 8;
        const unsigned short* bp = Kf + ((size_t)bh * NT + (bv ? kr : 0)) * 64 + lgrp * 8;
        bh8 af0 = av ? *(const bh8*)(ap) : zfrag;
        bh8 af1 = av ? *(const bh8*)(ap + 32) : zfrag;
        bh8 bf0 = bv ? *(const bh8*)(bp) : zfrag;
        bh8 bf1 = bv ? *(const bh8*)(bp + 32) : zfrag;
        fx4 acc = {0.f, 0.f, 0.f, 0.f};
        acc = __builtin_amdgcn_mfma_f32_16x16x32_bf16(af0, bf0, acc, 0, 0, 0);
        acc = __builtin_amdgcn_mfma_f32_16x16x32_bf16(af1, bf1, acc, 0, 0, 0);
#pragma unroll
        for (int r = 0; r < 4; ++r)
          Se[tr * 16 + lgrp * 4 + r][tc * 16 + lrow16] = acc[r];
      }
    }

    // ---- Pd: wave strip rows wv*16..+16, 4 col tiles ----
#pragma unroll
    for (int n = 0; n < 4; ++n) {
      const unsigned short* kb =
          kcf + ((size_t)bh * NT + c0 + n * 16 + lrow16) * 64 + lgrp * 8;
      bh8 kb0 = *(const bh8*)(kb);
      bh8 kb1 = *(const bh8*)(kb + 32);
      fx4 pacc = {0.f, 0.f, 0.f, 0.f};
      pacc = __builtin_amdgcn_mfma_f32_16x16x32_bf16(qa0, kb0, pacc, 0, 0, 0);
      pacc = __builtin_amdgcn_mfma_f32_16x16x32_bf16(qa1, kb1, pacc, 0, 0, 0);
#pragma unroll
      for (int r = 0; r < 4; ++r)
        Pd[wv * 16 + lgrp * 4 + r][n * 16 + lrow16] = f2bf(pacc[r]);
    }

    __syncthreads();   // Se/Pd visible

    // ---- tn slide + sim + online stats + store ----
    {
      float num = 0.f;
      for (int s = 0; s < 16; ++s) {
        int a_l = wv * 16 + s;
        int c_l = (a_l + lane) & 63;
        if (s == 0 || c_l == 0) {
          num = 0.f;
#pragma unroll
          for (int t = 0; t <= 16; ++t) num += Se[a_l + t][c_l + t];
        } else {
          num += Se[a_l + 16][c_l + 16] - Se[a_l - 1][c_l - 1];
        }
        int a = a0 + a_l, c = c0 + c_l;
        int mn = min(a, c), mx = max(a, c);
        float cnt = (float)(min(8, mn) + min(8, 1023 - mx) + 1);
        float sim = w0 * num / cnt + bf2f(Pd[a_l][c_l]);
        float tmax = sim;
#pragma unroll
        for (int off = 32; off; off >>= 1) tmax = fmaxf(tmax, __shfl_xor(tmax, off));
        float m_old = mrow[a_l];
        float m_new = fmaxf(m_old, tmax);
        float pe = __expf(sim - m_new);
        float ps = pe;
#pragma unroll
        for (int off = 32; off; off >>= 1) ps += __shfl_xor(ps, off);
        if (lane == 0) {
          lrow[a_l] = lrow[a_l] * __expf(m_old - m_new) + ps;
          mrow[a_l] = m_new;
        }
        attn[(((size_t)(b * NT + a)) * NH + hh) * NT + c] = sim;
      }
    }
  }
  __syncthreads();
  if (tid < 64) {
    ml[((size_t)bh * NT + a0 + tid) * 2] = mrow[tid];
    ml[((size_t)bh * NT + a0 + tid) * 2 + 1] = lrow[tid];
  }
}

// ---------------- softmax finalize + PV (unchanged fp32 path) ----------------
__global__ __launch_bounds__(256) void k_pv(
    const float* __restrict__ Vf, const float* __restrict__ ml,
    float* __restrict__ attn, float* __restrict__ deta)
{
  __shared__ float Pt[64][65];   // [c][a] transposed p
  __shared__ float Vt[64][68];   // [c][k]
  __shared__ float msh[64], lsh[64];
  const int at = blockIdx.x, bh = blockIdx.y;
  const int a0 = at * 64;
  const int b = bh >> 3, hh = bh & 7;
  const int tid = threadIdx.x;
  if (tid < 64) {
    msh[tid] = ml[((size_t)bh * NT + a0 + tid) * 2];
    lsh[tid] = 1.0f / ml[((size_t)bh * NT + a0 + tid) * 2 + 1];
  }
  float acc[4][4] = {};
  const int u = tid >> 4, v = tid & 15;
  for (int ct = 0; ct < 16; ++ct) {
    const int c0 = ct * 64;
    __syncthreads();
#pragma unroll
    for (int l4 = 0; l4 < 4; ++l4) {
      int idx = tid + l4 * 256;
      int r = idx >> 4, c4 = (idx & 15) << 2;
      size_t gaddr = (((size_t)(b * NT + a0 + r)) * NH + hh) * NT + c0 + c4;
      float4 sv = *(const float4*)(attn + gaddr);
      float m = msh[r], rl = lsh[r];
      float4 pv;
      pv.x = __expf(sv.x - m) * rl;
      pv.y = __expf(sv.y - m) * rl;
      pv.z = __expf(sv.z - m) * rl;
      pv.w = __expf(sv.w - m) * rl;
      *(float4*)(attn + gaddr) = pv;
      Pt[c4 + 0][r] = pv.x; Pt[c4 + 1][r] = pv.y; Pt[c4 + 2][r] = pv.z; Pt[c4 + 3][r] = pv.w;
      float4 vvv = *(const float4*)(Vf + ((size_t)bh * NT + c0 + r) * 64 + c4);
      *(float4*)&Vt[r][c4] = vvv;
    }
    __syncthreads();
    for (int cc = 0; cc < 64; ++cc) {
      float pa[4], vb[4];
#pragma unroll
      for (int i = 0; i < 4; ++i) pa[i] = Pt[cc][u * 4 + i];
      *(float4*)&vb[0] = *(const float4*)&Vt[cc][v * 4];
#pragma unroll
      for (int i = 0; i < 4; ++i)
#pragma unroll
        for (int j = 0; j < 4; ++j)
          acc[i][j] = fmaf(pa[i], vb[j], acc[i][j]);
    }
  }
#pragma unroll
  for (int i = 0; i < 4; ++i) {
    int a = a0 + u * 4 + i;
    float4 o;
    o.x = acc[i][0]; o.y = acc[i][1]; o.z = acc[i][2]; o.w = acc[i][3];
    *(float4*)(deta + ((size_t)(b * NT + a)) * DMODEL + hh * 64 + v * 4) = o;
  }
}

extern "C" void kernel_launch(void* const* d_in, const int* in_sizes, int n_in,
                              void* d_out, int out_size, void* d_ws, size_t ws_size,
                              hipStream_t stream) {
  const float* x   = (const float*)d_in[0];
  const float* aux = (const float*)d_in[1];
  const float* pos = (const float*)d_in[2];
  const float* Wq  = (const float*)d_in[3];
  const float* bq  = (const float*)d_in[4];
  const float* Wk  = (const float*)d_in[5];
  const float* bk  = (const float*)d_in[6];
  const float* Wv  = (const float*)d_in[7];
  const float* bv  = (const float*)d_in[8];
  const float* Wqa = (const float*)d_in[9];
  const float* bqa = (const float*)d_in[10];
  const float* Wka = (const float*)d_in[11];
  const float* bka = (const float*)d_in[12];
  const float* Wqp = (const float*)d_in[13];
  const float* bqp = (const float*)d_in[14];
  const float* Wkp = (const float*)d_in[15];
  const float* bkp = (const float*)d_in[16];
  const float* WO  = (const float*)d_in[17];
  const float* bO  = (const float*)d_in[18];
  const float* w   = (const float*)d_in[19];
  const float* wa  = (const float*)d_in[20];
  const float* wp  = (const float*)d_in[21];
  const int*   gdep = (const int*)d_in[22];

  float* out  = (float*)d_out;                        // [8,1024,512]
  float* attn = out + (size_t)4194304;                // [8,1024,8,1024]
  float* deta = out + (size_t)71303168;               // [8,1024,512]

  // temp raw GEMM outputs live in the (not yet written) attn region
  float* QKVraw = attn;                               // [8192,1536]
  float* APraw  = attn + (size_t)12582912;            // [8192,512]
  float* PPraw  = APraw + (size_t)4194304;            // [8192,256]

  // aliases: Qf (bf16) -> out slot, Kf (bf16) -> deta slot (both dead before overwrite)
  unsigned short* Qf = (unsigned short*)out;          // 8.4 MB < 16.8 MB slot
  unsigned short* Kf = (unsigned short*)deta;

  float* ws = (float*)d_ws;
  float* Wqkv_m = ws;                                 // 786432 f
  float* WO_m   = Wqkv_m + 786432;                    // 262144 f
  float* Vf     = WO_m + 262144;                      // 4194304 f
  float* mlb    = Vf + 4194304;                       // 131072 f
  unsigned short* qcf = (unsigned short*)(mlb + 131072);  // 4194304 u16
  unsigned short* kcf = qcf + 4194304;                    // 4194304 u16

  k_maskw<<<512, 256, 0, stream>>>(Wq, Wk, Wv, WO, gdep, Wqkv_m, WO_m);
  k_gemm<false><<<dim3(12, 64), 256, 0, stream>>>(x, Wqkv_m, QKVraw, 8192, 1536, 512, 1536, nullptr, nullptr);
  k_gemm<false><<<dim3(2, 64), 256, 0, stream>>>(aux, Wqa, APraw, 8192, 256, 256, 512, nullptr, nullptr);
  k_gemm<false><<<dim3(2, 64), 256, 0, stream>>>(aux, Wka, APraw + 256, 8192, 256, 256, 512, nullptr, nullptr);
  k_gemm<false><<<dim3(1, 64), 256, 0, stream>>>(pos, Wqp, PPraw, 8192, 128, 128, 256, nullptr, nullptr);
  k_gemm<false><<<dim3(1, 64), 256, 0, stream>>>(pos, Wkp, PPraw + 128, 8192, 128, 128, 256, nullptr, nullptr);
  k_combine_qkv<<<1024, 256, 0, stream>>>(QKVraw, bq, bk, bv, Qf, Kf, Vf);
  k_combine_ap<<<1024, 256, 0, stream>>>(APraw, PPraw, bqa, bka, bqp, bkp, wa, wp, qcf, kcf);
  k_sim<<<dim3(16, 64), 256, 0, stream>>>(Qf, Kf, qcf, kcf, w, mlb, attn);
  k_pv<<<dim3(16, 64), 256, 0, stream>>>(Vf, mlb, attn, deta);
  k_gemm<true><<<dim3(4, 64), 256, 0, stream>>>(deta, WO_m, out, 8192, 512, 512, 512, x, bO);
}

// Round 3
// 630.398 us; speedup vs baseline: 2.7526x; 1.4716x over previous
//
#include <hip/hip_runtime.h>
#include <math.h>

#define NB 8
#define NH 8
#define NT 1024
#define DMODEL 512

typedef short bh8 __attribute__((ext_vector_type(8)));   // 8 bf16 (4 VGPRs)
typedef float fx4 __attribute__((ext_vector_type(4)));   // MFMA accumulator

__device__ __forceinline__ unsigned short f2bf(float f) {
  union { float f; unsigned int u; } v; v.f = f;
  unsigned int u = v.u + 0x7FFFu + ((v.u >> 16) & 1u);
  return (unsigned short)(u >> 16);
}
__device__ __forceinline__ float bf2f(unsigned short h) {
  union { unsigned int u; float f; } v; v.u = ((unsigned int)h) << 16;
  return v.f;
}

// ---------------- prep: mask weights + convert everything to bf16 ----------------
__global__ __launch_bounds__(256) void k_prep(
    const float* __restrict__ Wq, const float* __restrict__ Wk,
    const float* __restrict__ Wv, const float* __restrict__ WO,
    const int* __restrict__ g,
    const float* __restrict__ Wqa, const float* __restrict__ Wka,
    const float* __restrict__ Wqp, const float* __restrict__ Wkp,
    const float* __restrict__ x, const float* __restrict__ aux, const float* __restrict__ pos,
    unsigned short* __restrict__ Wqkv_mb, unsigned short* __restrict__ WO_mb,
    unsigned short* __restrict__ Wab, unsigned short* __restrict__ Wpb,
    unsigned short* __restrict__ xb, unsigned short* __restrict__ auxb,
    unsigned short* __restrict__ posb)
{
  int stride = gridDim.x * 256;
  int tid0 = blockIdx.x * 256 + threadIdx.x;
  for (int i = tid0; i < 1536 * 512; i += stride) {
    int m = i & 511;
    int j = i >> 9;
    int k = j & 63;
    int hh = (j >> 6) & 7;
    int qkv = j >> 9;
    const float* W = (qkv == 0) ? Wq : (qkv == 1 ? Wk : Wv);
    Wqkv_mb[i] = f2bf(W[(hh * 64 + k) * 512 + m] * (float)g[k * 64 + (m & 63)]);
  }
  for (int i = tid0; i < 512 * 512; i += stride) {
    int d = i & 511, e = i >> 9;
    WO_mb[i] = f2bf(WO[i] * (float)g[(e & 63) * 64 + (d & 63)]);
  }
  for (int i = tid0; i < 131072; i += stride)
    Wab[i] = f2bf(i < 65536 ? Wqa[i] : Wka[i - 65536]);
  for (int i = tid0; i < 32768; i += stride)
    Wpb[i] = f2bf(i < 16384 ? Wqp[i] : Wkp[i - 16384]);
  for (int i = tid0; i < 1048576; i += stride) {
    float4 v = *(const float4*)(x + (size_t)i * 4);
    short4 s4; s4.x = f2bf(v.x); s4.y = f2bf(v.y); s4.z = f2bf(v.z); s4.w = f2bf(v.w);
    *(short4*)(xb + (size_t)i * 4) = s4;
  }
  for (int i = tid0; i < 524288; i += stride) {
    float4 v = *(const float4*)(aux + (size_t)i * 4);
    short4 s4; s4.x = f2bf(v.x); s4.y = f2bf(v.y); s4.z = f2bf(v.z); s4.w = f2bf(v.w);
    *(short4*)(auxb + (size_t)i * 4) = s4;
  }
  for (int i = tid0; i < 262144; i += stride) {
    float4 v = *(const float4*)(pos + (size_t)i * 4);
    short4 s4; s4.x = f2bf(v.x); s4.y = f2bf(v.y); s4.z = f2bf(v.z); s4.w = f2bf(v.w);
    *(short4*)(posb + (size_t)i * 4) = s4;
  }
}

// ---------------- direct-from-L2 bf16 MFMA GEMM: C[M,N] = A[M,K] * B[N,K]^T ----------------
// grid: (N/128, M/128), 256 threads (4 waves, 2x2 of 64x64 quadrants)
template<bool EPI>
__global__ __launch_bounds__(256) void k_bgemm(
    const unsigned short* __restrict__ A, const unsigned short* __restrict__ B,
    float* __restrict__ C, int K, int N,
    const float* __restrict__ X, const float* __restrict__ bias)
{
  const int bm = blockIdx.y * 128, bn = blockIdx.x * 128;
  const int tid = threadIdx.x, lane = tid & 63, wv = tid >> 6;
  const int wr = wv >> 1, wc = wv & 1;
  const int lrow = lane & 15, lgrp = lane >> 4;
  fx4 acc[4][4];
#pragma unroll
  for (int m = 0; m < 4; ++m)
#pragma unroll
    for (int n = 0; n < 4; ++n)
      acc[m][n] = (fx4){0.f, 0.f, 0.f, 0.f};
  const unsigned short* Ab = A + (size_t)(bm + wr * 64 + lrow) * K + lgrp * 8;
  const unsigned short* Bb = B + (size_t)(bn + wc * 64 + lrow) * K + lgrp * 8;
  for (int k0 = 0; k0 < K; k0 += 32) {
    bh8 af[4], bf[4];
#pragma unroll
    for (int m = 0; m < 4; ++m) af[m] = *(const bh8*)(Ab + (size_t)m * 16 * K + k0);
#pragma unroll
    for (int n = 0; n < 4; ++n) bf[n] = *(const bh8*)(Bb + (size_t)n * 16 * K + k0);
#pragma unroll
    for (int m = 0; m < 4; ++m)
#pragma unroll
      for (int n = 0; n < 4; ++n)
        acc[m][n] = __builtin_amdgcn_mfma_f32_16x16x32_bf16(af[m], bf[n], acc[m][n], 0, 0, 0);
  }
#pragma unroll
  for (int m = 0; m < 4; ++m)
#pragma unroll
    for (int n = 0; n < 4; ++n)
#pragma unroll
      for (int r = 0; r < 4; ++r) {
        int row = bm + wr * 64 + m * 16 + lgrp * 4 + r;
        int col = bn + wc * 64 + n * 16 + lrow;
        float v = acc[m][n][r];
        if (EPI) v += X[(size_t)row * N + col] + bias[col];
        C[(size_t)row * N + col] = v;
      }
}

// ---------------- combine QKV: bias + l2norm; Q *= w0; all bf16 out ----------------
__global__ __launch_bounds__(256) void k_combine_qkv(
    const float* __restrict__ raw, const float* __restrict__ bq,
    const float* __restrict__ bk, const float* __restrict__ bv,
    const float* __restrict__ w,
    unsigned short* __restrict__ Qf, unsigned short* __restrict__ Kf,
    unsigned short* __restrict__ Vrow)
{
  const float w0 = w[0];
  int wid = (blockIdx.x * 256 + threadIdx.x) >> 6;
  int lane = threadIdx.x & 63;
  int nw = (gridDim.x * 256) >> 6;
  const int total = NB * NT * 24;
  for (int v = wid; v < total; v += nw) {
    int bt = v / 24;
    int rem = v % 24;
    int qkv = rem >> 3, hh = rem & 7;
    float val = raw[(size_t)bt * 1536 + qkv * 512 + hh * 64 + lane];
    const float* bias = (qkv == 0) ? bq : (qkv == 1 ? bk : bv);
    val += bias[hh * 64 + lane];
    int b = bt >> 10, t = bt & 1023;
    size_t o = (((size_t)(b * 8 + hh) * NT) + t) * 64 + lane;
    if (qkv < 2) {
      float ss = val * val;
#pragma unroll
      for (int off = 32; off; off >>= 1) ss += __shfl_xor(ss, off);
      val /= fmaxf(sqrtf(ss), 1e-12f);
      if (qkv == 0) Qf[o] = f2bf(val * w0); else Kf[o] = f2bf(val);
    } else {
      Vrow[o] = f2bf(val);
    }
  }
}

// ---------------- combine aux/pos: bias + l2norm + fold wa/wp -> bf16 [bh][t][64] ----------------
__global__ __launch_bounds__(256) void k_combine_ap(
    const float* __restrict__ rawA, const float* __restrict__ rawP,
    const float* __restrict__ bqa, const float* __restrict__ bka,
    const float* __restrict__ bqp, const float* __restrict__ bkp,
    const float* __restrict__ wa, const float* __restrict__ wp,
    unsigned short* __restrict__ qcf, unsigned short* __restrict__ kcf)
{
  const float wa0 = wa[0], wp0 = wp[0];
  int wid = (blockIdx.x * 256 + threadIdx.x) >> 6;
  int lane = threadIdx.x & 63;
  int nw = (gridDim.x * 256) >> 6;
  const int total = NB * NT * NH;
  for (int v = wid; v < total; v += nw) {
    int bt = v >> 3, hh = v & 7;
    int b = bt >> 10, t = bt & 1023;
    size_t obase = (((size_t)(b * 8 + hh) * NT) + t) * 64;
    {
      int c = lane & 31;
      bool isK = lane >= 32;
      float val = rawA[(size_t)bt * 512 + (isK ? 256 : 0) + hh * 32 + c];
      val += (isK ? bka : bqa)[hh * 32 + c];
      float ss = val * val;
#pragma unroll
      for (int off = 16; off; off >>= 1) ss += __shfl_xor(ss, off, 32);
      val /= fmaxf(sqrtf(ss), 1e-12f);
      if (isK) kcf[obase + c] = f2bf(val); else qcf[obase + c] = f2bf(wa0 * val);
    }
    {
      int c = lane & 15;
      int grp = lane >> 4;
      if (grp < 2) {
        float val = rawP[(size_t)bt * 256 + (grp ? 128 : 0) + hh * 16 + c];
        val += (grp ? bkp : bqp)[hh * 16 + c];
        float ss = val * val;
#pragma unroll
        for (int off = 8; off; off >>= 1) ss += __shfl_xor(ss, off, 16);
        val /= fmaxf(sqrtf(ss), 1e-12f);
        if (grp) kcf[obase + 32 + c] = f2bf(val); else qcf[obase + 32 + c] = f2bf(wp0 * val);
      } else if (grp == 2) {
        qcf[obase + 48 + c] = 0;
      } else {
        kcf[obase + 48 + c] = 0;
      }
    }
  }
}

// ---------------- V transpose: Vrow[bh][t][64] -> Vt[bh][v][1024] ----------------
__global__ __launch_bounds__(256) void k_vtr(
    const unsigned short* __restrict__ Vrow, unsigned short* __restrict__ Vt)
{
  __shared__ unsigned short tile[64][72];
  const int tt = blockIdx.x, bh = blockIdx.y;
  const int tid = threadIdx.x;
  const int r = tid & 63, g = tid >> 6;
  const unsigned short* src = Vrow + ((size_t)bh * NT + tt * 64 + r) * 64 + g * 16;
  int4 v0 = *(const int4*)(src);
  int4 v1 = *(const int4*)(src + 8);
  const unsigned short* pv0 = (const unsigned short*)&v0;
  const unsigned short* pv1 = (const unsigned short*)&v1;
#pragma unroll
  for (int j = 0; j < 8; ++j) tile[g * 16 + j][r] = pv0[j];
#pragma unroll
  for (int j = 0; j < 8; ++j) tile[g * 16 + 8 + j][r] = pv1[j];
  __syncthreads();
  unsigned short* dst = Vt + ((size_t)bh * 64 + r) * NT + tt * 64 + g * 16;
  *(int4*)dst = *(const int4*)&tile[r][g * 16];
  *(int4*)(dst + 8) = *(const int4*)&tile[r][g * 16 + 8];
}

// ---------------- sim kernel: MFMA S-ext + MFMA Pd + slide + per-lane exp-sum ----------------
__global__ __launch_bounds__(256) void k_sim(
    const unsigned short* __restrict__ Qf, const unsigned short* __restrict__ Kf,
    const unsigned short* __restrict__ qcf, const unsigned short* __restrict__ kcf,
    float* __restrict__ lsum, float* __restrict__ attn)
{
  __shared__ float Se[80][81];
  __shared__ unsigned short Pd[64][66];
  const int at = blockIdx.x, bh = blockIdx.y;
  const int a0 = at * 64;
  const int b = bh >> 3, hh = bh & 7;
  const int tid = threadIdx.x;
  const int lane = tid & 63, wv = tid >> 6;
  const int lrow16 = lane & 15, lgrp = lane >> 4;
  const bh8 zfrag = {0, 0, 0, 0, 0, 0, 0, 0};
  const int base_cl = (wv * 16 + lane) & 63;
  float lacc[16];
#pragma unroll
  for (int s = 0; s < 16; ++s) lacc[s] = 0.f;

  bh8 qa0, qa1;
  {
    const unsigned short* qb =
        qcf + ((size_t)bh * NT + a0 + wv * 16 + lrow16) * 64 + lgrp * 8;
    qa0 = *(const bh8*)(qb);
    qa1 = *(const bh8*)(qb + 32);
  }

  for (int ct = 0; ct < 16; ++ct) {
    const int c0 = ct * 64;
    __syncthreads();

    // ---- Se: 25 ext tiles (16x16) over 4 waves ----
#pragma unroll
    for (int i = 0; i < 7; ++i) {
      int tt = wv + 4 * i;
      if (tt < 25) {
        int tr = tt / 5, tc = tt % 5;
        int ar = a0 - 8 + tr * 16 + lrow16;
        int kr = c0 - 8 + tc * 16 + lrow16;
        bool av = (unsigned)ar < (unsigned)NT;
        bool bv = (unsigned)kr < (unsigned)NT;
        const unsigned short* ap = Qf + ((size_t)bh * NT + (av ? ar : 0)) * 64 + lgrp * 8;
        const unsigned short* bp = Kf + ((size_t)bh * NT + (bv ? kr : 0)) * 64 + lgrp * 8;
        bh8 af0 = av ? *(const bh8*)(ap) : zfrag;
        bh8 af1 = av ? *(const bh8*)(ap + 32) : zfrag;
        bh8 bf0 = bv ? *(const bh8*)(bp) : zfrag;
        bh8 bf1 = bv ? *(const bh8*)(bp + 32) : zfrag;
        fx4 acc = {0.f, 0.f, 0.f, 0.f};
        acc = __builtin_amdgcn_mfma_f32_16x16x32_bf16(af0, bf0, acc, 0, 0, 0);
        acc = __builtin_amdgcn_mfma_f32_16x16x32_bf16(af1, bf1, acc, 0, 0, 0);
#pragma unroll
        for (int r = 0; r < 4; ++r)
          Se[tr * 16 + lgrp * 4 + r][tc * 16 + lrow16] = acc[r];
      }
    }

    // ---- Pd ----
#pragma unroll
    for (int n = 0; n < 4; ++n) {
      const unsigned short* kb =
          kcf + ((size_t)bh * NT + c0 + n * 16 + lrow16) * 64 + lgrp * 8;
      bh8 kb0 = *(const bh8*)(kb);
      bh8 kb1 = *(const bh8*)(kb + 32);
      fx4 pacc = {0.f, 0.f, 0.f, 0.f};
      pacc = __builtin_amdgcn_mfma_f32_16x16x32_bf16(qa0, kb0, pacc, 0, 0, 0);
      pacc = __builtin_amdgcn_mfma_f32_16x16x32_bf16(qa1, kb1, pacc, 0, 0, 0);
#pragma unroll
      for (int r = 0; r < 4; ++r)
        Pd[wv * 16 + lgrp * 4 + r][n * 16 + lrow16] = f2bf(pacc[r]);
    }

    __syncthreads();

    // ---- restart values D[s] for this wave's rows (lanes duplicate mod 16) ----
    float dval = 0.f;
    {
      int rr = wv * 16 + lrow16;
#pragma unroll
      for (int u = 0; u <= 16; ++u) dval += Se[rr + u][u];
    }

    // ---- slide + exp + per-lane sum + store ----
    float num = 0.f;
#pragma unroll
    for (int s = 0; s < 16; ++s) {
      int a_l = wv * 16 + s;
      int c_l = (base_cl + s) & 63;
      if (s == 0) {
        num = 0.f;
#pragma unroll
        for (int u = 0; u <= 16; ++u) num += Se[a_l + u][c_l + u];
      } else {
        int cm1 = (c_l == 0) ? 0 : (c_l - 1);
        float up = Se[a_l + 16][c_l + 16] - Se[a_l - 1][cm1];
        float dS = __shfl(dval, s);
        num = (c_l == 0) ? dS : (num + up);
      }
      int a = a0 + a_l, c = c0 + c_l;
      int mn = min(a, c), mx = max(a, c);
      float cntf = (float)(min(8, mn) + min(8, 1023 - mx) + 1);
      float sim = num * __builtin_amdgcn_rcpf(cntf) + bf2f(Pd[a_l][c_l]);
      float pe = __expf(sim);
      lacc[s] += pe;
      attn[(((size_t)(b * NT + a)) * NH + hh) * NT + c] = pe;
    }
  }

  // ---- final cross-lane reduce of row sums ----
#pragma unroll
  for (int s = 0; s < 16; ++s) {
    float v = lacc[s];
#pragma unroll
    for (int off = 32; off; off >>= 1) v += __shfl_xor(v, off);
    if (lane == 0) lsum[(size_t)bh * NT + a0 + wv * 16 + s] = v;
  }
}

// ---------------- normalize attn + PV via MFMA ----------------
__global__ __launch_bounds__(256) void k_pv(
    const unsigned short* __restrict__ Vt, const float* __restrict__ lsum,
    float* __restrict__ attn, float* __restrict__ deta,
    unsigned short* __restrict__ detab)
{
  const int at = blockIdx.x, bh = blockIdx.y;
  const int a0 = at * 64;
  const int b = bh >> 3, hh = bh & 7;
  const int tid = threadIdx.x, lane = tid & 63, wv = tid >> 6;
  const int lrow = lane & 15, lgrp = lane >> 4;
  const int arow = a0 + wv * 16 + lrow;
  const float rl = 1.0f / lsum[(size_t)bh * NT + arow];
  fx4 acc0 = {0.f,0.f,0.f,0.f}, acc1 = {0.f,0.f,0.f,0.f};
  fx4 acc2 = {0.f,0.f,0.f,0.f}, acc3 = {0.f,0.f,0.f,0.f};
  float* arowp = attn + (((size_t)(b * NT + arow)) * NH + hh) * NT;
  const unsigned short* vbase = Vt + (size_t)bh * 64 * NT;
  for (int ct = 0; ct < 16; ++ct) {
    const int c0 = ct * 64;
#pragma unroll
    for (int kh = 0; kh < 2; ++kh) {
      float* pp = arowp + c0 + kh * 32 + lgrp * 8;
      float4 p0 = *(float4*)pp;
      float4 p1 = *(float4*)(pp + 4);
      p0.x *= rl; p0.y *= rl; p0.z *= rl; p0.w *= rl;
      p1.x *= rl; p1.y *= rl; p1.z *= rl; p1.w *= rl;
      *(float4*)pp = p0;
      *(float4*)(pp + 4) = p1;
      bh8 af;
      unsigned short* afp = (unsigned short*)&af;
      afp[0] = f2bf(p0.x); afp[1] = f2bf(p0.y); afp[2] = f2bf(p0.z); afp[3] = f2bf(p0.w);
      afp[4] = f2bf(p1.x); afp[5] = f2bf(p1.y); afp[6] = f2bf(p1.z); afp[7] = f2bf(p1.w);
      const unsigned short* vk = vbase + c0 + kh * 32 + lgrp * 8;
      acc0 = __builtin_amdgcn_mfma_f32_16x16x32_bf16(af, *(const bh8*)(vk + (size_t)(0 * 16 + lrow) * NT), acc0, 0, 0, 0);
      acc1 = __builtin_amdgcn_mfma_f32_16x16x32_bf16(af, *(const bh8*)(vk + (size_t)(1 * 16 + lrow) * NT), acc1, 0, 0, 0);
      acc2 = __builtin_amdgcn_mfma_f32_16x16x32_bf16(af, *(const bh8*)(vk + (size_t)(2 * 16 + lrow) * NT), acc2, 0, 0, 0);
      acc3 = __builtin_amdgcn_mfma_f32_16x16x32_bf16(af, *(const bh8*)(vk + (size_t)(3 * 16 + lrow) * NT), acc3, 0, 0, 0);
    }
  }
  const int orow = a0 + wv * 16 + lgrp * 4;
#pragma unroll
  for (int r = 0; r < 4; ++r) {
    size_t rb = ((size_t)(b * NT + orow + r)) * DMODEL + hh * 64 + lrow;
    deta[rb + 0]  = acc0[r]; detab[rb + 0]  = f2bf(acc0[r]);
    deta[rb + 16] = acc1[r]; detab[rb + 16] = f2bf(acc1[r]);
    deta[rb + 32] = acc2[r]; detab[rb + 32] = f2bf(acc2[r]);
    deta[rb + 48] = acc3[r]; detab[rb + 48] = f2bf(acc3[r]);
  }
}

extern "C" void kernel_launch(void* const* d_in, const int* in_sizes, int n_in,
                              void* d_out, int out_size, void* d_ws, size_t ws_size,
                              hipStream_t stream) {
  const float* x   = (const float*)d_in[0];
  const float* aux = (const float*)d_in[1];
  const float* pos = (const float*)d_in[2];
  const float* Wq  = (const float*)d_in[3];
  const float* bq  = (const float*)d_in[4];
  const float* Wk  = (const float*)d_in[5];
  const float* bk  = (const float*)d_in[6];
  const float* Wv  = (const float*)d_in[7];
  const float* bv  = (const float*)d_in[8];
  const float* Wqa = (const float*)d_in[9];
  const float* bqa = (const float*)d_in[10];
  const float* Wka = (const float*)d_in[11];
  const float* bka = (const float*)d_in[12];
  const float* Wqp = (const float*)d_in[13];
  const float* bqp = (const float*)d_in[14];
  const float* Wkp = (const float*)d_in[15];
  const float* bkp = (const float*)d_in[16];
  const float* WO  = (const float*)d_in[17];
  const float* bO  = (const float*)d_in[18];
  const float* w   = (const float*)d_in[19];
  const float* wa  = (const float*)d_in[20];
  const float* wp  = (const float*)d_in[21];
  const int*   gdep = (const int*)d_in[22];

  float* out  = (float*)d_out;                        // [8,1024,512]
  float* attn = out + (size_t)4194304;                // [8,1024,8,1024]
  float* deta = out + (size_t)71303168;               // [8,1024,512]

  // temporaries living in the (not yet written) attn region
  float* QKVraw = attn;                               // [8192,1536] f32
  float* APraw  = attn + (size_t)12582912;            // [8192,512]  f32
  float* PPraw  = APraw + (size_t)4194304;            // [8192,256]  f32
  unsigned short* xb   = (unsigned short*)(PPraw + 2097152);  // [8192,512]  bf16
  unsigned short* auxb = xb + 4194304;                        // [8192,256]  bf16
  unsigned short* posb = auxb + 2097152;                      // [8192,128]  bf16

  // aliases: Qf -> out slot, Kf -> deta slot (both dead before overwrite)
  unsigned short* Qf = (unsigned short*)out;
  unsigned short* Kf = (unsigned short*)deta;

  float* ws = (float*)d_ws;
  float* lsum = ws;                                         // 65536 f32
  unsigned short* Wqkv_mb = (unsigned short*)(ws + 65536);  // 786432
  unsigned short* WO_mb   = Wqkv_mb + 786432;               // 262144
  unsigned short* Wab     = WO_mb + 262144;                 // 131072
  unsigned short* Wpb     = Wab + 131072;                   // 32768
  unsigned short* Vrow    = Wpb + 32768;                    // 4194304
  unsigned short* Vt      = Vrow + 4194304;                 // 4194304
  unsigned short* qcf     = Vt + 4194304;                   // 4194304
  unsigned short* kcf     = qcf + 4194304;                  // 4194304
  unsigned short* detab   = kcf + 4194304;                  // 4194304

  k_prep<<<512, 256, 0, stream>>>(Wq, Wk, Wv, WO, gdep, Wqa, Wka, Wqp, Wkp,
                                  x, aux, pos,
                                  Wqkv_mb, WO_mb, Wab, Wpb, xb, auxb, posb);
  k_bgemm<false><<<dim3(12, 64), 256, 0, stream>>>(xb, Wqkv_mb, QKVraw, 512, 1536, nullptr, nullptr);
  k_bgemm<false><<<dim3(4, 64), 256, 0, stream>>>(auxb, Wab, APraw, 256, 512, nullptr, nullptr);
  k_bgemm<false><<<dim3(2, 64), 256, 0, stream>>>(posb, Wpb, PPraw, 128, 256, nullptr, nullptr);
  k_combine_qkv<<<1024, 256, 0, stream>>>(QKVraw, bq, bk, bv, w, Qf, Kf, Vrow);
  k_combine_ap<<<1024, 256, 0, stream>>>(APraw, PPraw, bqa, bka, bqp, bkp, wa, wp, qcf, kcf);
  k_vtr<<<dim3(16, 64), 256, 0, stream>>>(Vrow, Vt);
  k_sim<<<dim3(16, 64), 256, 0, stream>>>(Qf, Kf, qcf, kcf, lsum, attn);
  k_pv<<<dim3(16, 64), 256, 0, stream>>>(Vt, lsum, attn, deta, detab);
  k_bgemm<true><<<dim3(4, 64), 256, 0, stream>>>(detab, WO_mb, out, 512, 512, x, bO);
}